// Round 12
// baseline (56.541 us; speedup 1.0000x reference)
//
#include <hip/hip_runtime.h>
#include <hip/hip_bf16.h>

typedef float  f32x4 __attribute__((ext_vector_type(4)));
typedef float  f32x8 __attribute__((ext_vector_type(8)));
typedef short  s8v   __attribute__((ext_vector_type(8)));
typedef __bf16 b8v   __attribute__((ext_vector_type(8)));
typedef unsigned int u32;
typedef unsigned short ushort;

#define T_DIM  2048
#define C_DIM  1024

// ---------- helpers ----------

typedef const __attribute__((address_space(1))) u32 gu32;
typedef __attribute__((address_space(3))) u32 lu32;

// async global->LDS, 16B per lane; LDS dest = uniform base + lane*16
static __device__ __forceinline__ void glds16(const void* g, void* l) {
  __builtin_amdgcn_global_load_lds((gu32*)g, (lu32*)l, 16, 0, 0);
}

static __device__ __forceinline__ b8v ldb8(const ushort* p) {
  return __builtin_bit_cast(b8v, *reinterpret_cast<const s8v*>(p));
}

static __device__ __forceinline__ b8v cvt8(f32x8 v) {
  b8v r;
#pragma unroll
  for (int i = 0; i < 8; ++i) r[i] = (__bf16)v[i];
  return r;
}

static __device__ __forceinline__ ushort bfu(float f) {
  __bf16 h = (__bf16)f;
  return __builtin_bit_cast(ushort, h);
}

static __device__ __forceinline__ f32x4 mfma16(b8v a, b8v b, f32x4 c) {
  return __builtin_amdgcn_mfma_f32_16x16x32_bf16(a, b, c, 0, 0, 0);
}

// raw barrier with counted vmcnt
#define BAR_VM(N)                                                        \
  asm volatile("s_waitcnt vmcnt(" #N ") lgkmcnt(0)" ::: "memory");       \
  __builtin_amdgcn_s_barrier();                                          \
  asm volatile("" ::: "memory");

// plain barrier (memory-fenced for the compiler, no waitcnt)
#define BAR_PLAIN                                                        \
  asm volatile("" ::: "memory");                                         \
  __builtin_amdgcn_s_barrier();                                          \
  asm volatile("" ::: "memory");

// ---------- kernel 0: W -> Wt bf16 transposed [3][128][1024] ----------
__global__ __launch_bounds__(256) void wconv(const float* __restrict__ Wq,
                                             const float* __restrict__ Wk,
                                             const float* __restrict__ Wv,
                                             ushort* __restrict__ Wt) {
  __shared__ float lds[64][65];
  const int m  = blockIdx.z;
  const int c0 = blockIdx.x * 64;
  const int h0 = blockIdx.y * 64;
  const float* W = (m == 0) ? Wq : (m == 1) ? Wk : Wv;

  const int cl = threadIdx.x >> 4;
  const int h4 = (threadIdx.x & 15) * 4;
#pragma unroll
  for (int i = 0; i < 4; ++i) {
    int c = cl + i * 16;
    float4 v = *reinterpret_cast<const float4*>(W + (c0 + c) * 128 + h0 + h4);
    lds[c][h4] = v.x; lds[c][h4 + 1] = v.y;
    lds[c][h4 + 2] = v.z; lds[c][h4 + 3] = v.w;
  }
  __syncthreads();
  const int hl = threadIdx.x >> 2;
  const int cs = (threadIdx.x & 3) * 16;
  s8v o0, o1;
#pragma unroll
  for (int i = 0; i < 8; ++i) o0[i] = (short)bfu(lds[cs + i][hl]);
#pragma unroll
  for (int i = 0; i < 8; ++i) o1[i] = (short)bfu(lds[cs + 8 + i][hl]);
  ushort* dst = Wt + (m * 128 + h0 + hl) * C_DIM + c0 + cs;
  *reinterpret_cast<s8v*>(dst) = o0;
  *reinterpret_cast<s8v*>(dst + 8) = o1;
}

// ---------- kernel 1: q/k/v projection (verified round-6 version) ----------
__global__ __launch_bounds__(256) void proj(const float* __restrict__ x,
                                            const ushort* __restrict__ Wt,
                                            ushort* __restrict__ q,
                                            ushort* __restrict__ k,
                                            ushort* __restrict__ vt) {
  __shared__ __align__(16) ushort Ab[2][32 * 72];
  __shared__ __align__(16) ushort Bb[2][128 * 64];
  __shared__ __align__(16) ushort stage[5120];

  const int t   = threadIdx.x;
  const int w   = t >> 6;
  const int lid = t & 63;
  const int lr  = lid & 15;
  const int g   = lid >> 4;
  const int wr  = w >> 1;
  const int wc  = w & 1;
  const int m   = blockIdx.y;
  const int r0  = blockIdx.x * 32;

  const int arow = t >> 3;
  const int acol = (t & 7) * 8;
  const float* ag = x + (r0 + arow) * C_DIM + acol;

  const int bswz = (((lid & 7) ^ (lid >> 3)) << 4);
  const char* bg = (const char*)(Wt + m * 128 * C_DIM);

  f32x4 acc[4] = {};

#pragma unroll
  for (int j = 0; j < 4; ++j) {
    int h = j * 32 + w * 8 + (lid >> 3);
    glds16(bg + h * 2048 + bswz, (char*)&Bb[0][0] + j * 4096 + w * 1024);
  }
  {
    f32x8 av = *reinterpret_cast<const f32x8*>(ag);
    b8v ac = cvt8(av);
    *reinterpret_cast<s8v*>(&Ab[0][arow * 72 + acol]) =
        __builtin_bit_cast(s8v, ac);
  }
  __syncthreads();

  int cur = 0;
#pragma unroll 1
  for (int i = 0; i < 16; ++i) {
    const int nxt = cur ^ 1;
    f32x8 an;
    if (i < 15) {
      const int kk = (i + 1) * 64;
#pragma unroll
      for (int j = 0; j < 4; ++j) {
        int h = j * 32 + w * 8 + (lid >> 3);
        glds16(bg + h * 2048 + kk * 2 + bswz,
               (char*)&Bb[nxt][0] + j * 4096 + w * 1024);
      }
      an = *reinterpret_cast<const f32x8*>(ag + kk);
    }

#pragma unroll
    for (int kk2 = 0; kk2 < 2; ++kk2) {
      b8v af = ldb8(&Ab[cur][(wr * 16 + lr) * 72 + kk2 * 32 + g * 8]);
#pragma unroll
      for (int cn = 0; cn < 4; ++cn) {
        int h = wc * 64 + cn * 16 + lr;
        int inner = (kk2 * 64 + g * 16) ^ ((h & 7) << 4);
        b8v bf = ldb8(
            (const ushort*)((const char*)&Bb[cur][h * 64] + inner));
        acc[cn] = mfma16(af, bf, acc[cn]);
      }
    }

    if (i < 15) {
      b8v anc = cvt8(an);
      *reinterpret_cast<s8v*>(&Ab[nxt][arow * 72 + acol]) =
          __builtin_bit_cast(s8v, anc);
    }
    __syncthreads();
    cur = nxt;
  }

  if (m < 2) {
#pragma unroll
    for (int cn = 0; cn < 4; ++cn)
#pragma unroll
      for (int j = 0; j < 4; ++j)
        stage[(wr * 16 + 4 * g + j) * 136 + wc * 64 + cn * 16 + lr] =
            bfu(acc[cn][j]);
    __syncthreads();
    ushort* dst = (m == 0) ? q : k;
#pragma unroll
    for (int c = 0; c < 2; ++c) {
      int chunk = c * 256 + t;
      int row = chunk >> 4, col8 = chunk & 15;
      s8v v8 = *reinterpret_cast<const s8v*>(&stage[row * 136 + col8 * 8]);
      *reinterpret_cast<s8v*>(&dst[(r0 + row) * 128 + col8 * 8]) = v8;
    }
  } else {
#pragma unroll
    for (int cn = 0; cn < 4; ++cn)
#pragma unroll
      for (int j = 0; j < 4; ++j)
        stage[(wc * 64 + cn * 16 + lr) * 40 + wr * 16 + 4 * g + j] =
            bfu(acc[cn][j]);
    __syncthreads();
    int b = blockIdx.x >> 6;
    int tbase = (blockIdx.x & 63) * 32;
#pragma unroll
    for (int c = 0; c < 2; ++c) {
      int chunk = c * 256 + t;
      int h = chunk >> 2, t8 = chunk & 3;
      s8v v8 = *reinterpret_cast<const s8v*>(&stage[h * 40 + t8 * 8]);
      *reinterpret_cast<s8v*>(&vt[(b * 128 + h) * T_DIM + tbase + t8 * 8]) = v8;
    }
  }
}

// ---------- kernel 2: flash attention, swapped-QK^T, P in registers ----------
// grid (128, 4) x 256 thr (4 waves). Block: 16 q-rows, kv sweeps 2048 in 32
// steps of 64. Waves = (wh in {0,1}: h-64 half) x (wk in {0,1}: kv-32 half).
// 2 LDS buffers (64 KB) -> 2 blocks/CU, 2 waves/SIMD. Per iter:
// [vmcnt(8)+bar] -> body(buf i&1) -> bar -> stage(i+2 -> buf i&1).
// Same swizzles/permutation as the verified round-11 kernel, qg dim dropped.
__global__ __launch_bounds__(256) void attn(const ushort* __restrict__ q,
                                            const ushort* __restrict__ k,
                                            const ushort* __restrict__ vt,
                                            float* __restrict__ out) {
  extern __shared__ __align__(16) char smem[];  // 2 x (K 16K + V 16K) = 64 KB

  const int t   = threadIdx.x;
  const int w   = t >> 6;
  const int lid = t & 63;
  const int lr  = lid & 15;
  const int g   = lid >> 4;
  const int wh  = w >> 1;   // h-64 half
  const int wk  = w & 1;    // kv-32 half
  const int b   = blockIdx.y;
  const int t0  = blockIdx.x * 16;

  // hoist Q fragments (B-operand), 16 q-rows
  const ushort* qp = q + (b * T_DIM + t0) * 128;
  b8v aq[4];
#pragma unroll
  for (int kf = 0; kf < 4; ++kf)
    aq[kf] = ldb8(&qp[lr * 128 + kf * 32 + g * 8]);

  // staging source pointers (lane-constant, minus the kv0 term)
  const char* kgb = (const char*)(k + b * T_DIM * 128);
  const char* vgb = (const char*)(vt + b * 128 * T_DIM);
  const char* ksrc[4];
  const char* vsrc[4];
#pragma unroll
  for (int j = 0; j < 4; ++j) {
    ksrc[j] = kgb + (16 * w + 4 * j + (lid >> 4)) * 256 +
              (((lid & 15) ^ (4 * j + (lid >> 4))) << 4);
    vsrc[j] = vgb + ((w * 4 + j) * 8 + (lid >> 3)) * 4096 +
              (((lid & 7) ^ (lid >> 3)) << 4);
  }

  // compute-side LDS byte offsets (within a buffer)
  const int rbase = wk * 32 + 8 * (lr >> 2) + (lr & 3);
  int koff[2][4], voff[4];
#pragma unroll
  for (int tt = 0; tt < 2; ++tt)
#pragma unroll
    for (int kf = 0; kf < 4; ++kf)
      koff[tt][kf] = (rbase + 4 * tt) * 256 +
                     (((kf * 4 + g) ^ ((rbase + 4 * tt) & 15)) << 4);
#pragma unroll
  for (int hf = 0; hf < 4; ++hf)
    voff[hf] = 16384 + (wh * 64 + hf * 16 + lr) * 128 +
               (((wk * 4 + g) ^ (lr & 7)) << 4);

  f32x4 of[4] = {};   // [hf]
  float lsum = 0.0f;
  const float scale = 0.08838834764831845f;  // 128^-0.5

#define ATTN_STAGE(KV0, BUF)                                              \
  _Pragma("unroll") for (int j = 0; j < 4; ++j)                           \
      glds16(ksrc[j] + (KV0) * 256,                                       \
             smem + (BUF) * 32768 + (w * 4 + j) * 1024);                  \
  _Pragma("unroll") for (int j = 0; j < 4; ++j)                           \
      glds16(vsrc[j] + (KV0) * 2,                                         \
             smem + (BUF) * 32768 + 16384 + (w * 4 + j) * 1024);

#define ATTN_BODY(BUF)                                                    \
  {                                                                       \
    const char* Kb = smem + (BUF) * 32768;                                \
    b8v kf0[4], kf1[4], vf[4];                                            \
    _Pragma("unroll") for (int kf = 0; kf < 4; ++kf)                      \
        kf0[kf] = ldb8((const ushort*)(Kb + koff[0][kf]));                \
    _Pragma("unroll") for (int kf = 0; kf < 4; ++kf)                      \
        kf1[kf] = ldb8((const ushort*)(Kb + koff[1][kf]));                \
    _Pragma("unroll") for (int hf = 0; hf < 4; ++hf)                      \
        vf[hf] = ldb8((const ushort*)(Kb + voff[hf]));                    \
    f32x4 s0 = {}, s1 = {};                                               \
    __builtin_amdgcn_s_setprio(1);                                        \
    _Pragma("unroll") for (int kf = 0; kf < 4; ++kf) {                    \
      s0 = mfma16(kf0[kf], aq[kf], s0);                                   \
      s1 = mfma16(kf1[kf], aq[kf], s1);                                   \
    }                                                                     \
    __builtin_amdgcn_s_setprio(0);                                        \
    b8v pk;                                                               \
    {                                                                     \
      float p0 = __expf(s0[0] * scale - 4.0f);                            \
      float p1 = __expf(s0[1] * scale - 4.0f);                            \
      float p2 = __expf(s0[2] * scale - 4.0f);                            \
      float p3 = __expf(s0[3] * scale - 4.0f);                            \
      float p4 = __expf(s1[0] * scale - 4.0f);                            \
      float p5 = __expf(s1[1] * scale - 4.0f);                            \
      float p6 = __expf(s1[2] * scale - 4.0f);                            \
      float p7 = __expf(s1[3] * scale - 4.0f);                            \
      lsum += ((p0 + p1) + (p2 + p3)) + ((p4 + p5) + (p6 + p7));          \
      pk[0] = (__bf16)p0; pk[1] = (__bf16)p1;                             \
      pk[2] = (__bf16)p2; pk[3] = (__bf16)p3;                             \
      pk[4] = (__bf16)p4; pk[5] = (__bf16)p5;                             \
      pk[6] = (__bf16)p6; pk[7] = (__bf16)p7;                             \
    }                                                                     \
    __builtin_amdgcn_s_setprio(1);                                        \
    _Pragma("unroll") for (int hf = 0; hf < 4; ++hf)                      \
        of[hf] = mfma16(pk, vf[hf], of[hf]);                              \
    __builtin_amdgcn_s_setprio(0);                                        \
  }

  // ---- prologue: 2 stages in flight ----
  ATTN_STAGE(0, 0)
  ATTN_STAGE(64, 1)

#pragma unroll 1
  for (int i = 0; i < 31; ++i) {
    BAR_VM(8)          // stage(i) landed (retires its 8)
    ATTN_BODY(i & 1)
    BAR_PLAIN          // all waves done reading buf(i&1)
    if (i < 30) { ATTN_STAGE((i + 2) * 64, i & 1) }
  }
  BAR_VM(0)
  ATTN_BODY(1)

#undef ATTN_STAGE
#undef ATTN_BODY

  // ---- reduce lsum over the 4 g-groups (kv slices) ----
  {
    float r = lsum;
    r += __shfl_xor(r, 16);
    r += __shfl_xor(r, 32);
    lsum = r;
  }

  // ---- merge across wk via LDS (aliases staging buffers; loop is done) ----
  float* lb = (float*)smem;           // [wk][16]
  float* ob = (float*)(smem + 256);   // [wh][16 q][64 h]
  __syncthreads();
  if (wh == 0 && g == 0) lb[wk * 16 + lr] = lsum;
  if (wk == 1) {
#pragma unroll
    for (int hf = 0; hf < 4; ++hf)
#pragma unroll
      for (int j = 0; j < 4; ++j)
        ob[(wh * 16 + 4 * g + j) * 64 + hf * 16 + lr] = of[hf][j];
  }
  __syncthreads();
  if (wk == 0) {
    float inv[4];
#pragma unroll
    for (int j = 0; j < 4; ++j)
      inv[j] = 1.0f / (lb[4 * g + j] + lb[16 + 4 * g + j]);
#pragma unroll
    for (int hf = 0; hf < 4; ++hf)
#pragma unroll
      for (int j = 0; j < 4; ++j) {
        int qrow = 4 * g + j;
        float val = of[hf][j] + ob[(wh * 16 + qrow) * 64 + hf * 16 + lr];
        out[(b * T_DIM + t0 + qrow) * 128 + wh * 64 + hf * 16 + lr] =
            val * inv[j];
      }
  }
}

// ---------- launcher ----------
extern "C" void kernel_launch(void* const* d_in, const int* in_sizes, int n_in,
                              void* d_out, int out_size, void* d_ws,
                              size_t ws_size, hipStream_t stream) {
  const float* x  = (const float*)d_in[0];
  const float* Wk = (const float*)d_in[1];
  const float* Wq = (const float*)d_in[2];
  const float* Wv = (const float*)d_in[3];
  float* out = (float*)d_out;

  char* ws = (char*)d_ws;
  ushort* Wt  = (ushort*)ws;                       // 0.75 MB
  ushort* qb  = (ushort*)(ws + (1u << 20));        // 2 MB
  ushort* kb  = (ushort*)(ws + 3u * (1u << 20));   // 2 MB
  ushort* vtb = (ushort*)(ws + 5u * (1u << 20));   // 2 MB

  (void)hipFuncSetAttribute(reinterpret_cast<const void*>(&attn),
                            hipFuncAttributeMaxDynamicSharedMemorySize, 65536);

  wconv<<<dim3(16, 2, 3), dim3(256), 0, stream>>>(Wq, Wk, Wv, Wt);
  proj<<<dim3(256, 3), dim3(256), 0, stream>>>(x, Wt, qb, kb, vtb);
  attn<<<dim3(128, 4), dim3(256), 65536, stream>>>(qb, kb, vtb, out);
}

// Round 14
// 51.624 us; speedup vs baseline: 1.0953x; 1.0953x over previous
//
#include <hip/hip_runtime.h>
#include <hip/hip_bf16.h>

typedef float  f32x4 __attribute__((ext_vector_type(4)));
typedef float  f32x8 __attribute__((ext_vector_type(8)));
typedef short  s8v   __attribute__((ext_vector_type(8)));
typedef __bf16 b8v   __attribute__((ext_vector_type(8)));
typedef unsigned int u32;
typedef unsigned short ushort;

#define T_DIM  2048
#define C_DIM  1024

// ---------- helpers ----------

typedef const __attribute__((address_space(1))) u32 gu32;
typedef __attribute__((address_space(3))) u32 lu32;

// async global->LDS, 16B per lane; LDS dest = uniform base + lane*16
static __device__ __forceinline__ void glds16(const void* g, void* l) {
  __builtin_amdgcn_global_load_lds((gu32*)g, (lu32*)l, 16, 0, 0);
}

static __device__ __forceinline__ b8v ldb8(const ushort* p) {
  return __builtin_bit_cast(b8v, *reinterpret_cast<const s8v*>(p));
}

static __device__ __forceinline__ b8v cvt8(f32x8 v) {
  b8v r;
#pragma unroll
  for (int i = 0; i < 8; ++i) r[i] = (__bf16)v[i];
  return r;
}

static __device__ __forceinline__ ushort bfu(float f) {
  __bf16 h = (__bf16)f;
  return __builtin_bit_cast(ushort, h);
}

static __device__ __forceinline__ f32x4 mfma16(b8v a, b8v b, f32x4 c) {
  return __builtin_amdgcn_mfma_f32_16x16x32_bf16(a, b, c, 0, 0, 0);
}

// raw barrier with counted vmcnt
#define BAR_VM(N)                                                        \
  asm volatile("s_waitcnt vmcnt(" #N ") lgkmcnt(0)" ::: "memory");       \
  __builtin_amdgcn_s_barrier();                                          \
  asm volatile("" ::: "memory");

// ---------- kernel 0: W -> Wt bf16 transposed [3][128][1024] ----------
__global__ __launch_bounds__(256) void wconv(const float* __restrict__ Wq,
                                             const float* __restrict__ Wk,
                                             const float* __restrict__ Wv,
                                             ushort* __restrict__ Wt) {
  __shared__ float lds[64][65];
  const int m  = blockIdx.z;
  const int c0 = blockIdx.x * 64;
  const int h0 = blockIdx.y * 64;
  const float* W = (m == 0) ? Wq : (m == 1) ? Wk : Wv;

  const int cl = threadIdx.x >> 4;
  const int h4 = (threadIdx.x & 15) * 4;
#pragma unroll
  for (int i = 0; i < 4; ++i) {
    int c = cl + i * 16;
    float4 v = *reinterpret_cast<const float4*>(W + (c0 + c) * 128 + h0 + h4);
    lds[c][h4] = v.x; lds[c][h4 + 1] = v.y;
    lds[c][h4 + 2] = v.z; lds[c][h4 + 3] = v.w;
  }
  __syncthreads();
  const int hl = threadIdx.x >> 2;
  const int cs = (threadIdx.x & 3) * 16;
  s8v o0, o1;
#pragma unroll
  for (int i = 0; i < 8; ++i) o0[i] = (short)bfu(lds[cs + i][hl]);
#pragma unroll
  for (int i = 0; i < 8; ++i) o1[i] = (short)bfu(lds[cs + 8 + i][hl]);
  ushort* dst = Wt + (m * 128 + h0 + hl) * C_DIM + c0 + cs;
  *reinterpret_cast<s8v*>(dst) = o0;
  *reinterpret_cast<s8v*>(dst + 8) = o1;
}

// ---------- kernel 1: q/k/v projection (verified round-6 version) ----------
__global__ __launch_bounds__(256) void proj(const float* __restrict__ x,
                                            const ushort* __restrict__ Wt,
                                            ushort* __restrict__ q,
                                            ushort* __restrict__ k,
                                            ushort* __restrict__ vt) {
  __shared__ __align__(16) ushort Ab[2][32 * 72];
  __shared__ __align__(16) ushort Bb[2][128 * 64];
  __shared__ __align__(16) ushort stage[5120];

  const int t   = threadIdx.x;
  const int w   = t >> 6;
  const int lid = t & 63;
  const int lr  = lid & 15;
  const int g   = lid >> 4;
  const int wr  = w >> 1;
  const int wc  = w & 1;
  const int m   = blockIdx.y;
  const int r0  = blockIdx.x * 32;

  const int arow = t >> 3;
  const int acol = (t & 7) * 8;
  const float* ag = x + (r0 + arow) * C_DIM + acol;

  const int bswz = (((lid & 7) ^ (lid >> 3)) << 4);
  const char* bg = (const char*)(Wt + m * 128 * C_DIM);

  f32x4 acc[4] = {};

#pragma unroll
  for (int j = 0; j < 4; ++j) {
    int h = j * 32 + w * 8 + (lid >> 3);
    glds16(bg + h * 2048 + bswz, (char*)&Bb[0][0] + j * 4096 + w * 1024);
  }
  {
    f32x8 av = *reinterpret_cast<const f32x8*>(ag);
    b8v ac = cvt8(av);
    *reinterpret_cast<s8v*>(&Ab[0][arow * 72 + acol]) =
        __builtin_bit_cast(s8v, ac);
  }
  __syncthreads();

  int cur = 0;
#pragma unroll 1
  for (int i = 0; i < 16; ++i) {
    const int nxt = cur ^ 1;
    f32x8 an;
    if (i < 15) {
      const int kk = (i + 1) * 64;
#pragma unroll
      for (int j = 0; j < 4; ++j) {
        int h = j * 32 + w * 8 + (lid >> 3);
        glds16(bg + h * 2048 + kk * 2 + bswz,
               (char*)&Bb[nxt][0] + j * 4096 + w * 1024);
      }
      an = *reinterpret_cast<const f32x8*>(ag + kk);
    }

#pragma unroll
    for (int kk2 = 0; kk2 < 2; ++kk2) {
      b8v af = ldb8(&Ab[cur][(wr * 16 + lr) * 72 + kk2 * 32 + g * 8]);
#pragma unroll
      for (int cn = 0; cn < 4; ++cn) {
        int h = wc * 64 + cn * 16 + lr;
        int inner = (kk2 * 64 + g * 16) ^ ((h & 7) << 4);
        b8v bf = ldb8(
            (const ushort*)((const char*)&Bb[cur][h * 64] + inner));
        acc[cn] = mfma16(af, bf, acc[cn]);
      }
    }

    if (i < 15) {
      b8v anc = cvt8(an);
      *reinterpret_cast<s8v*>(&Ab[nxt][arow * 72 + acol]) =
          __builtin_bit_cast(s8v, anc);
    }
    __syncthreads();
    cur = nxt;
  }

  if (m < 2) {
#pragma unroll
    for (int cn = 0; cn < 4; ++cn)
#pragma unroll
      for (int j = 0; j < 4; ++j)
        stage[(wr * 16 + 4 * g + j) * 136 + wc * 64 + cn * 16 + lr] =
            bfu(acc[cn][j]);
    __syncthreads();
    ushort* dst = (m == 0) ? q : k;
#pragma unroll
    for (int c = 0; c < 2; ++c) {
      int chunk = c * 256 + t;
      int row = chunk >> 4, col8 = chunk & 15;
      s8v v8 = *reinterpret_cast<const s8v*>(&stage[row * 136 + col8 * 8]);
      *reinterpret_cast<s8v*>(&dst[(r0 + row) * 128 + col8 * 8]) = v8;
    }
  } else {
#pragma unroll
    for (int cn = 0; cn < 4; ++cn)
#pragma unroll
      for (int j = 0; j < 4; ++j)
        stage[(wc * 64 + cn * 16 + lr) * 40 + wr * 16 + 4 * g + j] =
            bfu(acc[cn][j]);
    __syncthreads();
    int b = blockIdx.x >> 6;
    int tbase = (blockIdx.x & 63) * 32;
#pragma unroll
    for (int c = 0; c < 2; ++c) {
      int chunk = c * 256 + t;
      int h = chunk >> 2, t8 = chunk & 3;
      s8v v8 = *reinterpret_cast<const s8v*>(&stage[h * 40 + t8 * 8]);
      *reinterpret_cast<s8v*>(&vt[(b * 128 + h) * T_DIM + tbase + t8 * 8]) = v8;
    }
  }
}

// ---------- kernel 2: flash attention, 8-wave, swapped-QK^T, P in regs ----------
// grid (64, 4) x 512 thr (8 waves). Block: 32 q-rows, kv sweeps 2048 in 32
// steps of 64. Wave = (wq: q-16 half) x (wh: h-64 half) x (wk: kv-32 half).
// Per wave-iter: 4 glds stage (2 K + 2 V, each 1024 B), 12 b128 ds_reads,
// 8 QK^T + 4 PV MFMA, 8 exp. 3 K/V LDS buffers (96 KB), 2-deep vmcnt(4).
// 1 block/CU (minimal L2 traffic), 2 waves/SIMD.
// FIX vs round 13: K LDS dest stride (w*2+j)*1024 (was *2048 -> clobbered V).
__global__ __launch_bounds__(512) void attn(const ushort* __restrict__ q,
                                            const ushort* __restrict__ k,
                                            const ushort* __restrict__ vt,
                                            float* __restrict__ out) {
  extern __shared__ __align__(16) char smem[];  // 3 x (K 16K + V 16K) = 96 KB

  const int t   = threadIdx.x;
  const int w   = t >> 6;         // 0..7
  const int lid = t & 63;
  const int lr  = lid & 15;
  const int g   = lid >> 4;
  const int wq  = w >> 2;         // q-16 half
  const int wh  = (w >> 1) & 1;   // h-64 half
  const int wk  = w & 1;          // kv-32 half
  const int b   = blockIdx.y;
  const int t0  = blockIdx.x * 32;

  // hoist Q fragments (B-operand), this wave's 16 q-rows
  const ushort* qp = q + (b * T_DIM + t0 + wq * 16) * 128;
  b8v aq[4];
#pragma unroll
  for (int kf = 0; kf < 4; ++kf)
    aq[kf] = ldb8(&qp[lr * 128 + kf * 32 + g * 8]);

  // staging source pointers (lane-constant, minus the kv0 term)
  const char* kgb = (const char*)(k + b * T_DIM * 128);
  const char* vgb = (const char*)(vt + b * 128 * T_DIM);
  const char* ksrc[2];
  const char* vsrc[2];
#pragma unroll
  for (int j = 0; j < 2; ++j) {
    int krow = 8 * w + 4 * j + (lid >> 4);
    ksrc[j] = kgb + krow * 256 + (((lid & 15) ^ (krow & 15)) << 4);
    vsrc[j] = vgb + ((w * 2 + j) * 8 + (lid >> 3)) * 4096 +
              (((lid & 7) ^ (lid >> 3)) << 4);
  }

  // compute-side LDS byte offsets (within a buffer)
  const int rbase = wk * 32 + 8 * (lr >> 2) + (lr & 3);
  int koff[2][4], voff[4];
#pragma unroll
  for (int tt = 0; tt < 2; ++tt)
#pragma unroll
    for (int kf = 0; kf < 4; ++kf)
      koff[tt][kf] = (rbase + 4 * tt) * 256 +
                     (((kf * 4 + g) ^ ((rbase + 4 * tt) & 15)) << 4);
#pragma unroll
  for (int hf = 0; hf < 4; ++hf)
    voff[hf] = 16384 + (wh * 64 + hf * 16 + lr) * 128 +
               (((wk * 4 + g) ^ (lr & 7)) << 4);

  f32x4 of[4] = {};   // [hf]: q-16 x h-64, this wave's wk partial
  float lsum = 0.0f;
  const float scale = 0.08838834764831845f;  // 128^-0.5

#define ATTN_STAGE(KV0, BUF)                                              \
  _Pragma("unroll") for (int j = 0; j < 2; ++j)                           \
      glds16(ksrc[j] + (KV0) * 256,                                       \
             smem + (BUF) * 32768 + (w * 2 + j) * 1024);                  \
  _Pragma("unroll") for (int j = 0; j < 2; ++j)                           \
      glds16(vsrc[j] + (KV0) * 2,                                         \
             smem + (BUF) * 32768 + 16384 + (w * 2 + j) * 1024);

#define ATTN_BODY(BUF)                                                    \
  {                                                                       \
    const char* Kb = smem + (BUF) * 32768;                                \
    b8v kf0[4], kf1[4], vf[4];                                            \
    _Pragma("unroll") for (int kf = 0; kf < 4; ++kf)                      \
        kf0[kf] = ldb8((const ushort*)(Kb + koff[0][kf]));                \
    _Pragma("unroll") for (int kf = 0; kf < 4; ++kf)                      \
        kf1[kf] = ldb8((const ushort*)(Kb + koff[1][kf]));                \
    _Pragma("unroll") for (int hf = 0; hf < 4; ++hf)                      \
        vf[hf] = ldb8((const ushort*)(Kb + voff[hf]));                    \
    f32x4 s0 = {}, s1 = {};                                               \
    __builtin_amdgcn_s_setprio(1);                                        \
    _Pragma("unroll") for (int kf = 0; kf < 4; ++kf) {                    \
      s0 = mfma16(kf0[kf], aq[kf], s0);                                   \
      s1 = mfma16(kf1[kf], aq[kf], s1);                                   \
    }                                                                     \
    __builtin_amdgcn_s_setprio(0);                                        \
    b8v pk;                                                               \
    {                                                                     \
      float p0 = __expf(s0[0] * scale - 4.0f);                            \
      float p1 = __expf(s0[1] * scale - 4.0f);                            \
      float p2 = __expf(s0[2] * scale - 4.0f);                            \
      float p3 = __expf(s0[3] * scale - 4.0f);                            \
      float p4 = __expf(s1[0] * scale - 4.0f);                            \
      float p5 = __expf(s1[1] * scale - 4.0f);                            \
      float p6 = __expf(s1[2] * scale - 4.0f);                            \
      float p7 = __expf(s1[3] * scale - 4.0f);                            \
      lsum += ((p0 + p1) + (p2 + p3)) + ((p4 + p5) + (p6 + p7));          \
      pk[0] = (__bf16)p0; pk[1] = (__bf16)p1;                             \
      pk[2] = (__bf16)p2; pk[3] = (__bf16)p3;                             \
      pk[4] = (__bf16)p4; pk[5] = (__bf16)p5;                             \
      pk[6] = (__bf16)p6; pk[7] = (__bf16)p7;                             \
    }                                                                     \
    __builtin_amdgcn_s_setprio(1);                                        \
    _Pragma("unroll") for (int hf = 0; hf < 4; ++hf)                      \
        of[hf] = mfma16(pk, vf[hf], of[hf]);                              \
    __builtin_amdgcn_s_setprio(0);                                        \
  }

  // ---- prologue: 2 stages in flight ----
  ATTN_STAGE(0, 0)
  ATTN_STAGE(64, 1)

  int cur = 0;
#pragma unroll 1
  for (int i = 0; i < 31; ++i) {
    BAR_VM(4)  // own stage(i) done; stage(i+1) in flight; then barrier
    if (i < 30) {
      int nb = cur + 2; if (nb >= 3) nb -= 3;
      ATTN_STAGE((i + 2) * 64, nb)
    }
    ATTN_BODY(cur)
    ++cur; if (cur == 3) cur = 0;
  }
  BAR_VM(0)
  ATTN_BODY(cur)

#undef ATTN_STAGE
#undef ATTN_BODY

  // ---- reduce lsum over the 4 g-groups (kv slices within the wave) ----
  {
    float r = lsum;
    r += __shfl_xor(r, 16);
    r += __shfl_xor(r, 32);
    lsum = r;
  }

  // ---- merge across wk via LDS (aliases staging buffers; loop is done) ----
  float* lb = (float*)smem;           // [(wk*2+wq)*16 + row]
  float* ob = (float*)(smem + 256);   // [(wq*2+wh)*16 + row][64]
  __syncthreads();
  if (wh == 0 && g == 0) lb[(wk * 2 + wq) * 16 + lr] = lsum;
  if (wk == 1) {
#pragma unroll
    for (int hf = 0; hf < 4; ++hf)
#pragma unroll
      for (int j = 0; j < 4; ++j)
        ob[((wq * 2 + wh) * 16 + 4 * g + j) * 64 + hf * 16 + lr] = of[hf][j];
  }
  __syncthreads();
  if (wk == 0) {
    float inv[4];
#pragma unroll
    for (int j = 0; j < 4; ++j)
      inv[j] = 1.0f / (lb[(0 * 2 + wq) * 16 + 4 * g + j] +
                       lb[(1 * 2 + wq) * 16 + 4 * g + j]);
#pragma unroll
    for (int hf = 0; hf < 4; ++hf)
#pragma unroll
      for (int j = 0; j < 4; ++j) {
        int qrow = 4 * g + j;
        float val = of[hf][j] +
                    ob[((wq * 2 + wh) * 16 + qrow) * 64 + hf * 16 + lr];
        out[(b * T_DIM + t0 + wq * 16 + qrow) * 128 + wh * 64 + hf * 16 + lr] =
            val * inv[j];
      }
  }
}

// ---------- launcher ----------
extern "C" void kernel_launch(void* const* d_in, const int* in_sizes, int n_in,
                              void* d_out, int out_size, void* d_ws,
                              size_t ws_size, hipStream_t stream) {
  const float* x  = (const float*)d_in[0];
  const float* Wk = (const float*)d_in[1];
  const float* Wq = (const float*)d_in[2];
  const float* Wv = (const float*)d_in[3];
  float* out = (float*)d_out;

  char* ws = (char*)d_ws;
  ushort* Wt  = (ushort*)ws;                       // 0.75 MB
  ushort* qb  = (ushort*)(ws + (1u << 20));        // 2 MB
  ushort* kb  = (ushort*)(ws + 3u * (1u << 20));   // 2 MB
  ushort* vtb = (ushort*)(ws + 5u * (1u << 20));   // 2 MB

  (void)hipFuncSetAttribute(reinterpret_cast<const void*>(&attn),
                            hipFuncAttributeMaxDynamicSharedMemorySize, 98304);

  wconv<<<dim3(16, 2, 3), dim3(256), 0, stream>>>(Wq, Wk, Wv, Wt);
  proj<<<dim3(256, 3), dim3(256), 0, stream>>>(x, Wt, qb, kb, vtb);
  attn<<<dim3(64, 4), dim3(512), 98304, stream>>>(qb, kb, vtb, out);
}